// Round 1
// 394.376 us; speedup vs baseline: 1.2268x; 1.2268x over previous
//
#include <hip/hip_runtime.h>

#define KK 49        // 7*7
#define CH 128       // channels
#define NN 256       // tracks N
#define TT 16        // time

typedef __attribute__((ext_vector_type(8))) short bf16x8;
typedef __attribute__((ext_vector_type(4))) float f32x4;

__device__ __forceinline__ unsigned int f2bf(float f) {
    unsigned int u = __float_as_uint(f);
    return (u + 0x7fffu + ((u >> 16) & 1u)) >> 16;   // RNE fp32->bf16
}

__device__ __forceinline__ bf16x8 cvt8(f32x4 lo, f32x4 hi) {
    bf16x8 r;
    r[0] = (short)f2bf(lo[0]); r[1] = (short)f2bf(lo[1]);
    r[2] = (short)f2bf(lo[2]); r[3] = (short)f2bf(lo[3]);
    r[4] = (short)f2bf(hi[0]); r[5] = (short)f2bf(hi[1]);
    r[6] = (short)f2bf(hi[2]); r[7] = (short)f2bf(hi[3]);
    return r;
}

// One block per (level via grid.y, t, n). D-trick: D[g][ij] = fm[grid pixel g] . track[ij],
// g over the 8x8 integer pixel grid covering all bilinear corners of the 7x7 sample window.
// v2: track B-fragments loaded directly from global into registers (no Tr LDS, no staging
// phase, float4 loads); per-thread pixel coords (no pxs/pys LDS, no barrier before P
// staging). LDS ~18KB -> 8 blocks/CU (was 4). Barriers 4 -> 3.
__global__ __launch_bounds__(256, 8) void corr_mfma_kernel(
    const float* __restrict__ fm0, const float* __restrict__ tk0,
    const float* __restrict__ fm1, const float* __restrict__ tk1,
    const float* __restrict__ fm2, const float* __restrict__ tk2,
    const float* __restrict__ fm3, const float* __restrict__ tk3,
    const float* __restrict__ coords, float* __restrict__ out)
{
    const int lvl = blockIdx.y;
    const float* fm  = lvl == 0 ? fm0 : lvl == 1 ? fm1 : lvl == 2 ? fm2 : fm3;
    const float* trk = lvl == 0 ? tk0 : lvl == 1 ? tk1 : lvl == 2 ? tk2 : tk3;
    const int H = 96 >> lvl, W = 128 >> lvl;
    const float inv = 1.0f / (float)(1 << lvl);

    // P: bf16 [64 g][136 pitch] (17408 B) -> reused as D: f32 [64 g][68 pitch]
    __shared__ unsigned int smemPD[64 * 68];
    __shared__ int   rowoff[KK];             // (iy*8+ix)*68 per sample point
    __shared__ float wxs[KK], wys[KK];       // bilinear weights

    const int tid  = threadIdx.x;
    const int wave = tid >> 6;
    const int lane = tid & 63;
    const int t = blockIdx.x >> 8;
    const int n = blockIdx.x & 255;

    // coords broadcast to all threads (no LDS, no barrier dependency)
    const float2 c2 = *(const float2*)(coords + (size_t)(t * NN + n) * 2);
    const float cx = c2.x * inv;
    const float cy = c2.y * inv;
    const int gx0 = (int)floorf(cx) - 3;
    const int gy0 = (int)floorf(cy) - 3;

    // ---- B fragments: trk row ij = wave*16 + (lane&15) (clamped; cols 49..63 of D unused),
    //      channels q*8 + ks*32, contiguous in memory -> float4 loads, issued first ----
    const int mr = lane & 15;
    const int q  = lane >> 4;
    const int ij = min(wave * 16 + mr, KK - 1);
    const float* tb = trk + (size_t)ij * (NN * CH) + (size_t)n * CH + q * 8;
    const f32x4 bl0 = *(const f32x4*)(tb + 0 * 32);
    const f32x4 bh0 = *(const f32x4*)(tb + 0 * 32 + 4);
    const f32x4 bl1 = *(const f32x4*)(tb + 1 * 32);
    const f32x4 bh1 = *(const f32x4*)(tb + 1 * 32 + 4);
    const f32x4 bl2 = *(const f32x4*)(tb + 2 * 32);
    const f32x4 bh2 = *(const f32x4*)(tb + 2 * 32 + 4);
    const f32x4 bl3 = *(const f32x4*)(tb + 3 * 32);
    const f32x4 bh3 = *(const f32x4*)(tb + 3 * 32 + 4);

    // ---- Phase A: interp tables (VALU work overlapping B-load latency) ----
    if (tid < KK) {
        const int h = tid / 7;            // x-offset index
        const int w = tid - h * 7;        // y-offset index
        float x = fminf(fmaxf(cx + (float)(h - 3), 0.0f), (float)(W - 1));
        float y = fminf(fmaxf(cy + (float)(w - 3), 0.0f), (float)(H - 1));
        const float x0 = floorf(x), y0 = floorf(y);
        wxs[tid] = x - x0;
        wys[tid] = y - y0;
        const int ix = min(max((int)x0 - gx0, 0), 6);
        const int iy = min(max((int)y0 - gy0, 0), 6);
        rowoff[tid] = (iy * 8 + ix) * 68;
    }

    // convert B to bf16 fragments (frees the f32 regs before P staging)
    bf16x8 bfrag[4];
    bfrag[0] = cvt8(bl0, bh0);
    bfrag[1] = cvt8(bl1, bh1);
    bfrag[2] = cvt8(bl2, bh2);
    bfrag[3] = cvt8(bl3, bh3);

    // ---- P staging: P[g][c] = bf16(fm[t, c, py[g/8], px[g%8]]), per-thread coords ----
    {
        const int HW = H * W;
        const int py = min(max(gy0 + (lane >> 3), 0), H - 1);
        const int px = min(max(gx0 + (lane & 7), 0), W - 1);
        const float* base = fm + (size_t)t * CH * HW + (py * W + px);
        for (int j = wave; j < 64; j += 4) {            // j = channel pair
            const float a0 = base[(size_t)(2 * j) * HW];
            const float a1 = base[(size_t)(2 * j + 1) * HW];
            smemPD[lane * 68 + j] = f2bf(a0) | (f2bf(a1) << 16);
        }
    }
    __syncthreads();

    // ---- GEMM: D[64 g][64 ij] = P(64x128) x Tr^T(128x64), per-wave 16-col strip ----
    f32x4 acc[4];
    #pragma unroll
    for (int m = 0; m < 4; ++m) acc[m] = (f32x4){0.f, 0.f, 0.f, 0.f};
    {
        const unsigned short* P = (const unsigned short*)smemPD;  // pitch 136
        #pragma unroll
        for (int ks = 0; ks < 4; ++ks) {
            const int kof = ks * 32 + q * 8;
            #pragma unroll
            for (int m = 0; m < 4; ++m) {
                const bf16x8 a = *(const bf16x8*)&P[(m * 16 + mr) * 136 + kof];
                acc[m] = __builtin_amdgcn_mfma_f32_16x16x32_bf16(a, bfrag[ks], acc[m], 0, 0, 0);
            }
        }
    }
    __syncthreads();   // all waves done reading P before overwriting with D

    // ---- Spill D (C/D layout: col=lane&15, row=quad*4+reg) ----
    {
        float* D = (float*)smemPD;   // pitch 68
        const int col = wave * 16 + mr;
        #pragma unroll
        for (int m = 0; m < 4; ++m) {
            #pragma unroll
            for (int r = 0; r < 4; ++r) {
                D[(m * 16 + q * 4 + r) * 68 + col] = acc[m][r];
            }
        }
    }
    __syncthreads();

    // ---- Interp + store: out[p][ij] = bilinear of 4 D rows ----
    {
        const float* D = (const float*)smemPD;
        float* op = out + (((size_t)lvl * TT + t) * NN + n) * (KK * KK);
        for (int idx = tid; idx < KK * KK; idx += 256) {
            const int p   = idx / KK;
            const int ijc = idx - p * KK;
            const float wx = wxs[p], wy = wys[p];
            const float* d0 = &D[rowoff[p] + ijc];
            const float v00 = d0[0];
            const float v01 = d0[68];          // gx+1
            const float v10 = d0[8 * 68];      // gy+1
            const float v11 = d0[9 * 68];
            op[idx] = v00 * (1.f - wy) * (1.f - wx) + v01 * (1.f - wy) * wx
                    + v10 * wy * (1.f - wx)       + v11 * wy * wx;
        }
    }
}

extern "C" void kernel_launch(void* const* d_in, const int* in_sizes, int n_in,
                              void* d_out, int out_size, void* d_ws, size_t ws_size,
                              hipStream_t stream) {
    // setup_inputs() dict order (interleaved): fmaps0, track0, fmaps1, track1,
    // fmaps2, track2, fmaps3, track3, coords
    hipLaunchKernelGGL(corr_mfma_kernel, dim3(TT * NN, 4), dim3(256), 0, stream,
                       (const float*)d_in[0], (const float*)d_in[1],
                       (const float*)d_in[2], (const float*)d_in[3],
                       (const float*)d_in[4], (const float*)d_in[5],
                       (const float*)d_in[6], (const float*)d_in[7],
                       (const float*)d_in[8], (float*)d_out);
}

// Round 2
// 387.157 us; speedup vs baseline: 1.2497x; 1.0186x over previous
//
#include <hip/hip_runtime.h>

#define KK 49        // 7*7
#define CH 128       // channels
#define NN 256       // tracks N
#define TT 16        // time

typedef __attribute__((ext_vector_type(8))) short bf16x8;
typedef __attribute__((ext_vector_type(4))) float f32x4;
typedef __attribute__((ext_vector_type(4))) unsigned int u32x4;

// v_cvt_pk_bf16_f32: one VALU op converts 2 f32 -> packed 2x bf16 (RNE).
// Within-pair order is correctness-neutral here: A and B fragments use the
// identical pairing, so MFMA k-products match regardless of pack order.
__device__ __forceinline__ unsigned int cvt_pk(float a, float b) {
    unsigned int r;
    asm("v_cvt_pk_bf16_f32 %0, %1, %2" : "=v"(r) : "v"(a), "v"(b));
    return r;
}

// One block per (level via grid.y, t, n). D-trick: D[g][ij] = fm[grid pixel g] . track[ij],
// g over the 8x8 integer pixel grid covering all bilinear corners of the 7x7 sample window.
// v3: v_cvt_pk_bf16_f32 for all f32->bf16 (VALU ~8x less on conversion);
// P staging restructured so each thread fills 16 contiguous words of its row ->
// 4x ds_write_b128 (conflict-free: 32 banks x 8 = bandwidth minimum) instead of
// 16x ds_write_b32 (structurally 8-way conflicted: one-word-per-row writes can
// only reach 8 banks for any 16B-aligned pitch).
__global__ __launch_bounds__(256, 8) void corr_mfma_kernel(
    const float* __restrict__ fm0, const float* __restrict__ tk0,
    const float* __restrict__ fm1, const float* __restrict__ tk1,
    const float* __restrict__ fm2, const float* __restrict__ tk2,
    const float* __restrict__ fm3, const float* __restrict__ tk3,
    const float* __restrict__ coords, float* __restrict__ out)
{
    const int lvl = blockIdx.y;
    const float* fm  = lvl == 0 ? fm0 : lvl == 1 ? fm1 : lvl == 2 ? fm2 : fm3;
    const float* trk = lvl == 0 ? tk0 : lvl == 1 ? tk1 : lvl == 2 ? tk2 : tk3;
    const int H = 96 >> lvl, W = 128 >> lvl;
    const float inv = 1.0f / (float)(1 << lvl);

    // P: bf16 [64 g][136 pitch] (17408 B) -> reused as D: f32 [64 g][68 pitch]
    __shared__ unsigned int smemPD[64 * 68];
    __shared__ int   rowoff[KK];             // (iy*8+ix)*68 per sample point
    __shared__ float wxs[KK], wys[KK];       // bilinear weights

    const int tid  = threadIdx.x;
    const int wave = tid >> 6;
    const int lane = tid & 63;
    const int t = blockIdx.x >> 8;
    const int n = blockIdx.x & 255;

    const int mr = lane & 15;
    const int q  = lane >> 4;

    // ---- B loads first: independent of coords, deepest latency to hide.
    //      trk row ij = wave*16 + mr (clamped; D cols 49..63 never read),
    //      channels q*8 + ks*32 contiguous -> float4 loads ----
    const int ij = min(wave * 16 + mr, KK - 1);
    const float* tb = trk + (size_t)ij * (NN * CH) + (size_t)n * CH + q * 8;
    f32x4 bl[4], bh[4];
    #pragma unroll
    for (int ks = 0; ks < 4; ++ks) {
        bl[ks] = *(const f32x4*)(tb + ks * 32);
        bh[ks] = *(const f32x4*)(tb + ks * 32 + 4);
    }

    // coords broadcast to all threads
    const float2 c2 = *(const float2*)(coords + (size_t)(t * NN + n) * 2);
    const float cx = c2.x * inv;
    const float cy = c2.y * inv;
    const int gx0 = (int)floorf(cx) - 3;
    const int gy0 = (int)floorf(cy) - 3;

    // ---- Phase A: interp tables (VALU work overlapping B-load latency) ----
    if (tid < KK) {
        const int h = tid / 7;            // x-offset index
        const int w = tid - h * 7;        // y-offset index
        float x = fminf(fmaxf(cx + (float)(h - 3), 0.0f), (float)(W - 1));
        float y = fminf(fmaxf(cy + (float)(w - 3), 0.0f), (float)(H - 1));
        const float x0 = floorf(x), y0 = floorf(y);
        wxs[tid] = x - x0;
        wys[tid] = y - y0;
        const int ix = min(max((int)x0 - gx0, 0), 6);
        const int iy = min(max((int)y0 - gy0, 0), 6);
        rowoff[tid] = (iy * 8 + ix) * 68;
    }

    // ---- convert B to bf16 fragments (1 cvt_pk per 2 floats) ----
    bf16x8 bfrag[4];
    #pragma unroll
    for (int ks = 0; ks < 4; ++ks) {
        union { bf16x8 v; u32x4 u; } bu;
        bu.u[0] = cvt_pk(bl[ks][0], bl[ks][1]);
        bu.u[1] = cvt_pk(bl[ks][2], bl[ks][3]);
        bu.u[2] = cvt_pk(bh[ks][0], bh[ks][1]);
        bu.u[3] = cvt_pk(bh[ks][2], bh[ks][3]);
        bfrag[ks] = bu.v;
    }

    // ---- P staging: P[g][c] = bf16(fm[t, c, py[g>>3], px[g&7]]).
    //      Thread (wave, lane=g) fills word columns [16*wave, 16*wave+16) of row g:
    //      per c4: 8 scattered channel loads -> 4 cvt_pk -> 1 ds_write_b128 ----
    {
        const int HW = H * W;
        const int py = min(max(gy0 + (lane >> 3), 0), H - 1);
        const int px = min(max(gx0 + (lane & 7), 0), W - 1);
        const float* base = fm + (size_t)t * CH * HW + (py * W + px);
        const int j0 = wave * 16;         // first word column this thread fills
        #pragma unroll
        for (int c4 = 0; c4 < 4; ++c4) {
            const int jb = j0 + c4 * 4;   // word column of this 16B chunk
            float a[8];
            #pragma unroll
            for (int i = 0; i < 8; ++i)
                a[i] = base[(size_t)(2 * jb + i) * HW];
            u32x4 wv;
            wv[0] = cvt_pk(a[0], a[1]);
            wv[1] = cvt_pk(a[2], a[3]);
            wv[2] = cvt_pk(a[4], a[5]);
            wv[3] = cvt_pk(a[6], a[7]);
            *(u32x4*)&smemPD[lane * 68 + jb] = wv;   // 16B aligned, conflict-free
        }
    }
    __syncthreads();

    // ---- GEMM: D[64 g][64 ij] = P(64x128) x Tr^T(128x64), per-wave 16-col strip ----
    f32x4 acc[4];
    #pragma unroll
    for (int m = 0; m < 4; ++m) acc[m] = (f32x4){0.f, 0.f, 0.f, 0.f};
    {
        const unsigned short* P = (const unsigned short*)smemPD;  // pitch 136
        #pragma unroll
        for (int ks = 0; ks < 4; ++ks) {
            const int kof = ks * 32 + q * 8;
            #pragma unroll
            for (int m = 0; m < 4; ++m) {
                const bf16x8 a = *(const bf16x8*)&P[(m * 16 + mr) * 136 + kof];
                acc[m] = __builtin_amdgcn_mfma_f32_16x16x32_bf16(a, bfrag[ks], acc[m], 0, 0, 0);
            }
        }
    }
    __syncthreads();   // all waves done reading P before overwriting with D

    // ---- Spill D (C/D layout: col=lane&15, row=quad*4+reg) ----
    {
        float* D = (float*)smemPD;   // pitch 68
        const int col = wave * 16 + mr;
        #pragma unroll
        for (int m = 0; m < 4; ++m) {
            #pragma unroll
            for (int r = 0; r < 4; ++r) {
                D[(m * 16 + q * 4 + r) * 68 + col] = acc[m][r];
            }
        }
    }
    __syncthreads();

    // ---- Interp + store: out[p][ij] = bilinear of 4 D rows ----
    {
        const float* D = (const float*)smemPD;
        float* op = out + (((size_t)lvl * TT + t) * NN + n) * (KK * KK);
        for (int idx = tid; idx < KK * KK; idx += 256) {
            const int p   = idx / KK;
            const int ijc = idx - p * KK;
            const float wx = wxs[p], wy = wys[p];
            const float* d0 = &D[rowoff[p] + ijc];
            const float v00 = d0[0];
            const float v01 = d0[68];          // gx+1
            const float v10 = d0[8 * 68];      // gy+1
            const float v11 = d0[9 * 68];
            op[idx] = v00 * (1.f - wy) * (1.f - wx) + v01 * (1.f - wy) * wx
                    + v10 * wy * (1.f - wx)       + v11 * wy * wx;
        }
    }
}

extern "C" void kernel_launch(void* const* d_in, const int* in_sizes, int n_in,
                              void* d_out, int out_size, void* d_ws, size_t ws_size,
                              hipStream_t stream) {
    // setup_inputs() dict order (interleaved): fmaps0, track0, fmaps1, track1,
    // fmaps2, track2, fmaps3, track3, coords
    hipLaunchKernelGGL(corr_mfma_kernel, dim3(TT * NN, 4), dim3(256), 0, stream,
                       (const float*)d_in[0], (const float*)d_in[1],
                       (const float*)d_in[2], (const float*)d_in[3],
                       (const float*)d_in[4], (const float*)d_in[5],
                       (const float*)d_in[6], (const float*)d_in[7],
                       (const float*)d_in[8], (float*)d_out);
}